// Round 2
// baseline (750.416 us; speedup 1.0000x reference)
//
#include <hip/hip_runtime.h>
#include <math.h>

// Problem constants
#define B_ 4
#define N_ 325
#define T_ 288
#define F2_ 64
#define H_ 8
#define PATCH_ 12
#define L_ 24
#define TOPK_ 5
#define BN_ (B_*N_)          // 1300

// Scratch offsets inside d_out's new_values region (floats).
// All are consumed before the final kernel overwrites the region.
#define NV_LEN 23961600
#define OQ   0                // q: BN*H*L = 249600
#define OKk  249600           // k: 249600
#define OVS  499200           // v_small [bn][h][t]: BN*H*T = 2995200
#define OS   3494400          // s [bn][t]: 374400
#define OQG  3868800          // Qg [bn][128]: 166400
#define OKG2 4035200          // Kg2 [bn][128]: 166400
// Real output offsets
#define ODELAY 23961600       // 52000
#define OTC    24013600       // 52000
#define OADJ2  24065600       // 422500

// ws offsets (floats). Total need: 377192 floats = 1.51 MB.
#define WU    0               // u [bn][t]: 374400
#define WSQ   374400          // 1300
#define WSK   375700          // 1300
#define WWSUM 377000          // 64
#define WGW   377064          // 128

// Reduce 8 per-lane accumulators (lane=f over 64 f's) to 8 sums.
// Returns output[lane>>3] on every lane; lanes with (lane&7)==0 hold valid h=lane>>3.
__device__ __forceinline__ float reduce8(float acc[8], int lane) {
#pragma unroll
  for (int h = 0; h < 8; ++h) {
    acc[h] += __shfl_xor(acc[h], 32);
    acc[h] += __shfl_xor(acc[h], 16);
    acc[h] += __shfl_xor(acc[h], 8);
  }
  int g = lane >> 3;
  float s0 = (g & 1) ? acc[1] : acc[0];
  float s1 = (g & 1) ? acc[3] : acc[2];
  float s2 = (g & 1) ? acc[5] : acc[4];
  float s3 = (g & 1) ? acc[7] : acc[6];
  float t0 = (g & 2) ? s1 : s0;
  float t1 = (g & 2) ? s3 : s2;
  float v  = (g & 4) ? t1 : t0;
  v += __shfl_xor(v, 4);
  v += __shfl_xor(v, 2);
  v += __shfl_xor(v, 1);
  return v;
}

// K0: wsum[f] = sum_c Wout_map[f,c]; gw[h] = sum_f wsum[f]*gWg[f,h]
__global__ __launch_bounds__(128) void k0_wsum_gw(const float* __restrict__ Wout_map,
                                                  const float* __restrict__ gWg,
                                                  float* __restrict__ ws) {
  __shared__ float wsum_s[64];
  int tid = threadIdx.x;
  if (tid < 64) {
    float a = 0.f;
#pragma unroll
    for (int c = 0; c < 8; ++c) a += Wout_map[tid * 8 + c];
    wsum_s[tid] = a;
    ws[WWSUM + tid] = a;
  }
  __syncthreads();
  float g = 0.f;
  for (int f = 0; f < 64; ++f) g += wsum_s[f] * gWg[f * 128 + tid];
  ws[WGW + tid] = g;
}

// K1: q[bn,h,l] = sum_{p,f} X[bn, l*12+p, f] * W[h,f,p]  for both Q and K
__global__ __launch_bounds__(256) void k1_qkproj(const float* __restrict__ Qin,
                                                 const float* __restrict__ Kin,
                                                 const float* __restrict__ Wq,
                                                 const float* __restrict__ Wk,
                                                 float* outbuf) {
  __shared__ float wt[6144];  // [h][p][f] transposed weights
  int bn = blockIdx.x;
  int tid = threadIdx.x;
  int lane = tid & 63;
  int w = tid >> 6;
  for (int phase = 0; phase < 2; ++phase) {
    const float* W = phase ? Wk : Wq;
    const float* X = phase ? Kin : Qin;
    float* qout = outbuf + (phase ? OKk : OQ);
    if (phase) __syncthreads();  // protect wt before restaging
    for (int i = tid; i < 6144; i += 256) {
      int h = i / 768, r = i % 768, f = r / 12, p = r % 12;
      wt[h * 768 + p * 64 + f] = W[i];
    }
    __syncthreads();
    for (int l = w; l < 24; l += 4) {
      float acc[8] = {0, 0, 0, 0, 0, 0, 0, 0};
      const float* xrow = X + ((size_t)bn * 288 + l * 12) * 64;
#pragma unroll
      for (int p = 0; p < 12; ++p) {
        float x = xrow[p * 64 + lane];
#pragma unroll
        for (int h = 0; h < 8; ++h) acc[h] += x * wt[h * 768 + p * 64 + lane];
      }
      float v = reduce8(acc, lane);
      if ((lane & 7) == 0) {
        int h = lane >> 3;
        qout[(bn * 8 + h) * 24 + l] = v;
      }
    }
  }
}

// K2: v_small[bn,h,t] = sum_f V[bn,t,f] * Wv[h,f]
__global__ __launch_bounds__(256) void k2_vproj(const float* __restrict__ Vin,
                                                const float* __restrict__ Wv,
                                                float* outbuf) {
  __shared__ float wv[512];
  int bn = blockIdx.x, tid = threadIdx.x, lane = tid & 63, w = tid >> 6;
  wv[tid] = Wv[tid];
  wv[tid + 256] = Wv[tid + 256];
  __syncthreads();
  float* vs = outbuf + OVS;
  for (int t = w; t < 288; t += 4) {
    float x = Vin[((size_t)bn * 288 + t) * 64 + lane];
    float acc[8];
#pragma unroll
    for (int h = 0; h < 8; ++h) acc[h] = x * wv[h * 64 + lane];
    float v = reduce8(acc, lane);
    if ((lane & 7) == 0) vs[(bn * 8 + (lane >> 3)) * 288 + t] = v;
  }
}

// K3: circular correlation over L=24, top-5 (strict >, first-index tie), softmax.
__global__ __launch_bounds__(256) void k3_corr_topk(const float* buf, float* out) {
  int row = blockIdx.x * 256 + threadIdx.x;  // (b,n,h) row
  if (row >= BN_ * H_) return;
  const float* q = buf + OQ + row * 24;
  const float* k = buf + OKk + row * 24;
  float qv[24], kv[24];
#pragma unroll
  for (int m = 0; m < 24; ++m) { qv[m] = q[m]; kv[m] = k[m]; }
  float corr[24];
#pragma unroll
  for (int l = 0; l < 24; ++l) {
    float a = 0.f;
#pragma unroll
    for (int m = 0; m < 24; ++m) a += qv[m] * kv[(m - l + 24) % 24];
    corr[l] = a;
  }
  int idx[5]; float wv_[5];
  int i0 = -1, i1 = -1, i2 = -1, i3 = -1;
#pragma unroll
  for (int j = 0; j < 5; ++j) {
    float best = -3.0e38f; int bi = 0;
#pragma unroll
    for (int l = 0; l < 24; ++l) {
      bool taken = (l == i0) | (l == i1) | (l == i2) | (l == i3);
      if (!taken && corr[l] > best) { best = corr[l]; bi = l; }
    }
    idx[j] = bi; wv_[j] = best;
    if (j == 0) i0 = bi; else if (j == 1) i1 = bi;
    else if (j == 2) i2 = bi; else if (j == 3) i3 = bi;
  }
  float mx = wv_[0];  // descending order -> first is max
  float e[5], ssum = 0.f;
#pragma unroll
  for (int j = 0; j < 5; ++j) { e[j] = expf(wv_[j] - mx); ssum += e[j]; }
  float inv = 1.0f / ssum;
#pragma unroll
  for (int j = 0; j < 5; ++j) {
    out[ODELAY + row * 5 + j] = (float)(idx[j] * 12);
    out[OTC + row * 5 + j] = e[j] * inv;
  }
}

// K4: s[bn,t] = (1/8) sum_h sum_i tc[h,i]*v_small[bn,h,(d+t)%T]; also sq,sk reductions
__global__ __launch_bounds__(320) void k4_s(const float* __restrict__ gQ1,
                                            const float* __restrict__ gK1,
                                            float* out, float* __restrict__ ws) {
  int bn = blockIdx.x, tid = threadIdx.x;
  __shared__ float tc_s[40];
  __shared__ int d_s[40];
  __shared__ float r1[5], r2[5];
  if (tid < 40) {
    tc_s[tid] = out[OTC + bn * 40 + tid];
    d_s[tid] = (int)(out[ODELAY + bn * 40 + tid] + 0.5f);
  }
  __syncthreads();
  int t = tid;
  float sval = 0.f;
  if (t < 288) {
    const float* vsb = out + OVS + (size_t)bn * 8 * 288;
    float acc = 0.f;
#pragma unroll
    for (int h = 0; h < 8; ++h) {
      const float* vr = vsb + h * 288;
#pragma unroll
      for (int i = 0; i < 5; ++i) {
        int ix = d_s[h * 5 + i] + t;
        if (ix >= 288) ix -= 288;
        acc += tc_s[h * 5 + i] * vr[ix];
      }
    }
    sval = 0.125f * acc;
    out[OS + bn * 288 + t] = sval;
  }
  float a1 = (t < 288) ? sval * gQ1[t] : 0.f;
  float a2 = (t < 288) ? sval * gK1[t] : 0.f;
#pragma unroll
  for (int off = 32; off; off >>= 1) { a1 += __shfl_xor(a1, off); a2 += __shfl_xor(a2, off); }
  int w = tid >> 6, lane = tid & 63;
  if (lane == 0) { r1[w] = a1; r2[w] = a2; }
  __syncthreads();
  if (tid == 0) {
    float s1 = 0.f, s2 = 0.f;
#pragma unroll
    for (int i = 0; i < 5; ++i) { s1 += r1[i]; s2 += r2[i]; }
    ws[WSQ + bn] = s1;
    ws[WSK + bn] = s2;
  }
}

// K5: Qg[bn,h] = sum_f gQ2[h,f]*relu(wsum[f]*sq); Kg2[bn,h] = sum_g gWa[h,g]*Kg[bn,g]
__global__ __launch_bounds__(128) void k5_qkg(const float* __restrict__ gQ2,
                                              const float* __restrict__ gK2,
                                              const float* __restrict__ gWa,
                                              float* out, const float* __restrict__ ws) {
  int bn = blockIdx.x, h = threadIdx.x;
  __shared__ float qg[64], kg[64], kgv[128];
  float sq = ws[WSQ + bn], sk = ws[WSK + bn];
  if (h < 64) {
    float wsm = ws[WWSUM + h];
    qg[h] = fmaxf(wsm * sq, 0.f);
    kg[h] = fmaxf(wsm * sk, 0.f);
  }
  __syncthreads();
  float Qv = 0.f, Kv = 0.f;
  const float4* gq4 = (const float4*)(gQ2 + h * 64);
  const float4* gk4 = (const float4*)(gK2 + h * 64);
  const float4* qg4 = (const float4*)qg;
  const float4* kg4 = (const float4*)kg;
#pragma unroll
  for (int i = 0; i < 16; ++i) {
    float4 a = gq4[i], x = qg4[i];
    Qv += a.x * x.x + a.y * x.y + a.z * x.z + a.w * x.w;
    float4 b = gk4[i], y = kg4[i];
    Kv += b.x * y.x + b.y * y.y + b.z * y.z + b.w * y.w;
  }
  kgv[h] = Kv;
  __syncthreads();
  float K2v = 0.f;
  const float4* wa4 = (const float4*)(gWa + h * 128);
  const float4* kv4 = (const float4*)kgv;
#pragma unroll
  for (int i = 0; i < 32; ++i) {
    float4 a = wa4[i], x = kv4[i];
    K2v += a.x * x.x + a.y * x.y + a.z * x.z + a.w * x.w;
  }
  out[OQG + bn * 128 + h] = Qv;
  out[OKG2 + bn * 128 + h] = K2v;
}

// K6: logits[m] = Qg[bn,:]·Kg2[b,m,:]; softmax over m; *adj -> adj2
__global__ __launch_bounds__(384) void k6_attn(const float* __restrict__ adj, float* out) {
  int bn = blockIdx.x, b = bn / N_, n = bn % N_, tid = threadIdx.x;
  __shared__ float qs[128];
  __shared__ float red1[6], red2[6];
  if (tid < 128) qs[tid] = out[OQG + bn * 128 + tid];
  __syncthreads();
  int m = tid;
  float logit = -3.0e38f;
  if (m < N_) {
    const float4* kr = (const float4*)(out + OKG2 + ((size_t)b * N_ + m) * 128);
    const float4* q4 = (const float4*)qs;
    float a = 0.f;
#pragma unroll
    for (int i = 0; i < 32; ++i) {
      float4 x = kr[i], y = q4[i];
      a += x.x * y.x + x.y * y.y + x.z * y.z + x.w * y.w;
    }
    logit = a;
  }
  float v = logit;
#pragma unroll
  for (int off = 32; off; off >>= 1) v = fmaxf(v, __shfl_xor(v, off));
  int w = tid >> 6, lane = tid & 63;
  if (lane == 0) red1[w] = v;
  __syncthreads();
  float mx = red1[0];
#pragma unroll
  for (int i = 1; i < 6; ++i) mx = fmaxf(mx, red1[i]);
  float ev = (m < N_) ? expf(logit - mx) : 0.f;
  float sv = ev;
#pragma unroll
  for (int off = 32; off; off >>= 1) sv += __shfl_xor(sv, off);
  if (lane == 0) red2[w] = sv;
  __syncthreads();
  float total = 0.f;
#pragma unroll
  for (int i = 0; i < 6; ++i) total += red2[i];
  if (m < N_) out[OADJ2 + (size_t)bn * N_ + m] = (ev / total) * adj[n * N_ + m];
}

// K7: u[bn,t] = sum_m adj2[bn,m] * s[b,m,t]
__global__ __launch_bounds__(320) void k7_u(const float* out, float* __restrict__ ws) {
  int bn = blockIdx.x, b = bn / N_, tid = threadIdx.x;
  __shared__ float arow[N_];
  for (int i = tid; i < N_; i += 320) arow[i] = out[OADJ2 + (size_t)bn * N_ + i];
  __syncthreads();
  if (tid < 288) {
    const float* sb = out + OS + (size_t)b * N_ * 288 + tid;
    float acc = 0.f;
    for (int m = 0; m < N_; ++m) acc += arow[m] * sb[(size_t)m * 288];
    ws[WU + bn * 288 + tid] = acc;
  }
}

// K8: new_values[bn,t,f] = sum_h gelu(u[bn,t]*gw[h]) * gWout[h,f]
__global__ __launch_bounds__(256) void k8_final(const float* __restrict__ gWout,
                                                const float* __restrict__ ws,
                                                float* __restrict__ out) {
  __shared__ float wo[128 * 64];    // gWout staged
  __shared__ float pl[32 * 130];    // p[t][h], padded stride to avoid bank conflicts
  __shared__ float gwl[128];
  __shared__ float ul[32];
  int blk = blockIdx.x;
  int bn = blk / 9, t0 = (blk % 9) * 32;
  int tid = threadIdx.x;
  const float4* src = (const float4*)gWout;
  float4* dst = (float4*)wo;
  for (int i = tid; i < 2048; i += 256) dst[i] = src[i];
  if (tid < 128) gwl[tid] = ws[WGW + tid];
  if (tid < 32) ul[tid] = ws[WU + bn * 288 + t0 + tid];
  __syncthreads();
#pragma unroll
  for (int j = 0; j < 16; ++j) {
    int i = tid + j * 256;
    int t = i >> 7, h = i & 127;
    float x = ul[t] * gwl[h];
    pl[t * 130 + h] = 0.5f * x * (1.0f + erff(x * 0.7071067811865475f));
  }
  __syncthreads();
  int tq = tid >> 4, fq = tid & 15;
  float4 acc0 = {0, 0, 0, 0}, acc1 = {0, 0, 0, 0};
#pragma unroll 8
  for (int h = 0; h < 128; ++h) {
    float4 wv = *(const float4*)&wo[h * 64 + fq * 4];
    float p0 = pl[tq * 130 + h];
    float p1 = pl[(tq + 16) * 130 + h];
    acc0.x += p0 * wv.x; acc0.y += p0 * wv.y; acc0.z += p0 * wv.z; acc0.w += p0 * wv.w;
    acc1.x += p1 * wv.x; acc1.y += p1 * wv.y; acc1.z += p1 * wv.z; acc1.w += p1 * wv.w;
  }
  size_t base = ((size_t)bn * 288 + t0) * 64;
  *(float4*)&out[base + (size_t)tq * 64 + fq * 4] = acc0;
  *(float4*)&out[base + (size_t)(tq + 16) * 64 + fq * 4] = acc1;
}

extern "C" void kernel_launch(void* const* d_in, const int* in_sizes, int n_in,
                              void* d_out, int out_size, void* d_ws, size_t ws_size,
                              hipStream_t stream) {
  const float* Qin = (const float*)d_in[0];
  const float* Kin = (const float*)d_in[1];
  const float* Vin = (const float*)d_in[2];
  const float* adj = (const float*)d_in[3];
  const float* Wq  = (const float*)d_in[4];
  const float* Wk  = (const float*)d_in[5];
  const float* Wv  = (const float*)d_in[6];
  const float* Wout_map = (const float*)d_in[7];
  const float* gQ1 = (const float*)d_in[8];
  const float* gQ2 = (const float*)d_in[9];
  const float* gK1 = (const float*)d_in[10];
  const float* gK2 = (const float*)d_in[11];
  const float* gWa = (const float*)d_in[12];
  const float* gWg = (const float*)d_in[13];
  const float* gWout = (const float*)d_in[14];
  float* out = (float*)d_out;
  float* ws = (float*)d_ws;  // needs ~1.51 MB

  k0_wsum_gw<<<1, 128, 0, stream>>>(Wout_map, gWg, ws);
  k1_qkproj<<<BN_, 256, 0, stream>>>(Qin, Kin, Wq, Wk, out);
  k2_vproj<<<BN_, 256, 0, stream>>>(Vin, Wv, out);
  k3_corr_topk<<<(BN_ * H_ + 255) / 256, 256, 0, stream>>>(out, out);
  k4_s<<<BN_, 320, 0, stream>>>(gQ1, gK1, out, ws);
  k5_qkg<<<BN_, 128, 0, stream>>>(gQ2, gK2, gWa, out, ws);
  k6_attn<<<BN_, 384, 0, stream>>>(adj, out);
  k7_u<<<BN_, 320, 0, stream>>>(out, ws);
  k8_final<<<BN_ * 9, 256, 0, stream>>>(gWout, ws, out);
}

// Round 3
// 651.569 us; speedup vs baseline: 1.1517x; 1.1517x over previous
//
#include <hip/hip_runtime.h>
#include <math.h>

// Problem constants
#define B_ 4
#define N_ 325
#define T_ 288
#define F2_ 64
#define H_ 8
#define PATCH_ 12
#define L_ 24
#define TOPK_ 5
#define BN_ (B_*N_)          // 1300

// Scratch offsets inside d_out's new_values region (floats).
// All consumed before k8 overwrites the region.
#define NV_LEN 23961600
#define OW2Q 499200           // transposed Wq [8][768]
#define OW2K 505344           // transposed Wk [8][768]
#define OS   3494400          // s [bn][t]: 374400
#define OQG  3868800          // Qg [bn][128]
#define OKG2 4035200          // Kg2 [bn][128]
// Real output offsets
#define ODELAY 23961600       // 52000
#define OTC    24013600       // 52000
#define OADJ2  24065600       // 422500

// ws offsets (floats). Total 377192 floats = 1.51 MB.
#define WU    0               // u [bn][t]: 374400
#define WSQ   374400          // 1300
#define WSK   375700          // 1300
#define WWSUM 377000          // 64
#define WGW   377064          // 128

// K0: wsum, gw, and weight transposes W2[h][p*64+f] = W[h][f][p]
__global__ __launch_bounds__(128) void k0_prep(const float* __restrict__ Wout_map,
                                               const float* __restrict__ gWg,
                                               const float* __restrict__ Wq,
                                               const float* __restrict__ Wk,
                                               float* __restrict__ ws,
                                               float* __restrict__ out) {
  __shared__ float wsum_s[64];
  int tid = threadIdx.x;
  if (tid < 64) {
    float a = 0.f;
#pragma unroll
    for (int c = 0; c < 8; ++c) a += Wout_map[tid * 8 + c];
    wsum_s[tid] = a;
    ws[WWSUM + tid] = a;
  }
  __syncthreads();
  float g = 0.f;
  for (int f = 0; f < 64; ++f) g += wsum_s[f] * gWg[f * 128 + tid];
  ws[WGW + tid] = g;
  // transpose weights: dst i = h*768 + p*64 + f ; src = h*768 + f*12 + p
  for (int i = tid; i < 6144; i += 128) {
    int h = i / 768, r = i % 768, p = r >> 6, f = r & 63;
    int src = h * 768 + f * 12 + p;
    out[OW2Q + i] = Wq[src];
    out[OW2K + i] = Wk[src];
  }
}

// K1: fused qk-projection + circular corr + top-5 + softmax.
// Wave w handles heads {2w, 2w+1}. Lane's 12 input elems: e = c*256 + lane*4 + j.
__global__ __launch_bounds__(256, 2) void k1_fused(const float* __restrict__ Qin,
                                                   const float* __restrict__ Kin,
                                                   float* out) {
  __shared__ float qs[8][24], ks[8][24], cs[8][24];
  int bn = blockIdx.x, tid = threadIdx.x, lane = tid & 63, w = tid >> 6;
  int h0 = 2 * w, h1 = 2 * w + 1;
  // loop-invariant weights in registers (12 per head per input = 48 VGPR)
  float4 wq0[3], wq1[3], wk0[3], wk1[3];
#pragma unroll
  for (int c = 0; c < 3; ++c) {
    wq0[c] = *(const float4*)&out[OW2Q + h0 * 768 + c * 256 + lane * 4];
    wq1[c] = *(const float4*)&out[OW2Q + h1 * 768 + c * 256 + lane * 4];
    wk0[c] = *(const float4*)&out[OW2K + h0 * 768 + c * 256 + lane * 4];
    wk1[c] = *(const float4*)&out[OW2K + h1 * 768 + c * 256 + lane * 4];
  }
  const float* Qb = Qin + (size_t)bn * 18432;
  const float* Kb = Kin + (size_t)bn * 18432;
#pragma unroll 2
  for (int l = 0; l < 24; ++l) {
    float4 xq[3], xk[3];
#pragma unroll
    for (int c = 0; c < 3; ++c) {
      xq[c] = *(const float4*)&Qb[l * 768 + c * 256 + lane * 4];
      xk[c] = *(const float4*)&Kb[l * 768 + c * 256 + lane * 4];
    }
    float aq0 = 0.f, aq1 = 0.f, ak0 = 0.f, ak1 = 0.f;
#pragma unroll
    for (int c = 0; c < 3; ++c) {
      aq0 += xq[c].x * wq0[c].x + xq[c].y * wq0[c].y + xq[c].z * wq0[c].z + xq[c].w * wq0[c].w;
      aq1 += xq[c].x * wq1[c].x + xq[c].y * wq1[c].y + xq[c].z * wq1[c].z + xq[c].w * wq1[c].w;
      ak0 += xk[c].x * wk0[c].x + xk[c].y * wk0[c].y + xk[c].z * wk0[c].z + xk[c].w * wk0[c].w;
      ak1 += xk[c].x * wk1[c].x + xk[c].y * wk1[c].y + xk[c].z * wk1[c].z + xk[c].w * wk1[c].w;
    }
#pragma unroll
    for (int off = 32; off; off >>= 1) {
      aq0 += __shfl_xor(aq0, off);
      aq1 += __shfl_xor(aq1, off);
      ak0 += __shfl_xor(ak0, off);
      ak1 += __shfl_xor(ak1, off);
    }
    if (lane == 0) {
      qs[h0][l] = aq0; qs[h1][l] = aq1;
      ks[h0][l] = ak0; ks[h1][l] = ak1;
    }
  }
  __syncthreads();
  // circular correlation: corr[h][l] = sum_m q[h][m]*k[h][(m-l+24)%24]
  if (tid < 192) {
    int h = tid / 24, l = tid % 24;
    float a = 0.f;
#pragma unroll
    for (int m = 0; m < 24; ++m) a += qs[h][m] * ks[h][(m - l + 24) % 24];
    cs[h][l] = a;
  }
  __syncthreads();
  if (tid < 8) {
    int h = tid;
    float corr[24];
#pragma unroll
    for (int l = 0; l < 24; ++l) corr[l] = cs[h][l];
    int idx[5]; float wv_[5];
    int i0 = -1, i1 = -1, i2 = -1, i3 = -1;
#pragma unroll
    for (int j = 0; j < 5; ++j) {
      float best = -3.0e38f; int bi = 0;
#pragma unroll
      for (int l = 0; l < 24; ++l) {
        bool taken = (l == i0) | (l == i1) | (l == i2) | (l == i3);
        if (!taken && corr[l] > best) { best = corr[l]; bi = l; }
      }
      idx[j] = bi; wv_[j] = best;
      if (j == 0) i0 = bi; else if (j == 1) i1 = bi;
      else if (j == 2) i2 = bi; else if (j == 3) i3 = bi;
    }
    float mx = wv_[0];
    float e[5], ssum = 0.f;
#pragma unroll
    for (int j = 0; j < 5; ++j) { e[j] = expf(wv_[j] - mx); ssum += e[j]; }
    float inv = 1.0f / ssum;
    int row = bn * 8 + h;
#pragma unroll
    for (int j = 0; j < 5; ++j) {
      out[ODELAY + row * 5 + j] = (float)(idx[j] * 12);
      out[OTC + row * 5 + j] = e[j] * inv;
    }
  }
}

// K2: fused v-projection (into LDS) + delay-gather weighted sum -> s, sq, sk.
__global__ __launch_bounds__(256, 4) void k2_vs(const float* __restrict__ Vin,
                                                const float* __restrict__ Wv,
                                                const float* __restrict__ gQ1,
                                                const float* __restrict__ gK1,
                                                float* out, float* __restrict__ ws) {
  __shared__ float vs[8][288];
  __shared__ float tc_s[40];
  __shared__ int d_s[40];
  __shared__ float r1[4], r2[4];
  int bn = blockIdx.x, tid = threadIdx.x, lane = tid & 63, w = tid >> 6;
  int f4 = lane & 15, tof = lane >> 4;
  int h0 = 2 * w, h1 = 2 * w + 1;
  if (tid < 40) {
    tc_s[tid] = out[OTC + bn * 40 + tid];
    d_s[tid] = (int)(out[ODELAY + bn * 40 + tid] + 0.5f);
  }
  float4 wv0 = *(const float4*)&Wv[h0 * 64 + f4 * 4];
  float4 wv1 = *(const float4*)&Wv[h1 * 64 + f4 * 4];
  const float* Vb = Vin + (size_t)bn * 18432;
#pragma unroll 4
  for (int t0 = 0; t0 < 288; t0 += 4) {
    int t = t0 + tof;
    float4 x = *(const float4*)&Vb[t * 64 + f4 * 4];
    float a0 = x.x * wv0.x + x.y * wv0.y + x.z * wv0.z + x.w * wv0.w;
    float a1 = x.x * wv1.x + x.y * wv1.y + x.z * wv1.z + x.w * wv1.w;
#pragma unroll
    for (int off = 8; off; off >>= 1) {
      a0 += __shfl_xor(a0, off);
      a1 += __shfl_xor(a1, off);
    }
    if (f4 == 0) { vs[h0][t] = a0; vs[h1][t] = a1; }
  }
  __syncthreads();
  float p1 = 0.f, p2 = 0.f;
  for (int t = tid; t < 288; t += 256) {
    float acc = 0.f;
#pragma unroll
    for (int h = 0; h < 8; ++h) {
#pragma unroll
      for (int i = 0; i < 5; ++i) {
        int ix = d_s[h * 5 + i] + t;
        if (ix >= 288) ix -= 288;
        acc += tc_s[h * 5 + i] * vs[h][ix];
      }
    }
    float sval = 0.125f * acc;
    out[OS + bn * 288 + t] = sval;
    p1 += sval * gQ1[t];
    p2 += sval * gK1[t];
  }
#pragma unroll
  for (int off = 32; off; off >>= 1) { p1 += __shfl_xor(p1, off); p2 += __shfl_xor(p2, off); }
  if (lane == 0) { r1[w] = p1; r2[w] = p2; }
  __syncthreads();
  if (tid == 0) {
    float s1 = 0.f, s2 = 0.f;
#pragma unroll
    for (int i = 0; i < 4; ++i) { s1 += r1[i]; s2 += r2[i]; }
    ws[WSQ + bn] = s1;
    ws[WSK + bn] = s2;
  }
}

// K5: Qg[bn,h] = sum_f gQ2[h,f]*relu(wsum[f]*sq); Kg2[bn,h] = sum_g gWa[h,g]*Kg[bn,g]
__global__ __launch_bounds__(128) void k5_qkg(const float* __restrict__ gQ2,
                                              const float* __restrict__ gK2,
                                              const float* __restrict__ gWa,
                                              float* out, const float* __restrict__ ws) {
  int bn = blockIdx.x, h = threadIdx.x;
  __shared__ float qg[64], kg[64], kgv[128];
  float sq = ws[WSQ + bn], sk = ws[WSK + bn];
  if (h < 64) {
    float wsm = ws[WWSUM + h];
    qg[h] = fmaxf(wsm * sq, 0.f);
    kg[h] = fmaxf(wsm * sk, 0.f);
  }
  __syncthreads();
  float Qv = 0.f, Kv = 0.f;
  const float4* gq4 = (const float4*)(gQ2 + h * 64);
  const float4* gk4 = (const float4*)(gK2 + h * 64);
  const float4* qg4 = (const float4*)qg;
  const float4* kg4 = (const float4*)kg;
#pragma unroll
  for (int i = 0; i < 16; ++i) {
    float4 a = gq4[i], x = qg4[i];
    Qv += a.x * x.x + a.y * x.y + a.z * x.z + a.w * x.w;
    float4 b = gk4[i], y = kg4[i];
    Kv += b.x * y.x + b.y * y.y + b.z * y.z + b.w * y.w;
  }
  kgv[h] = Kv;
  __syncthreads();
  float K2v = 0.f;
  const float4* wa4 = (const float4*)(gWa + h * 128);
  const float4* kv4 = (const float4*)kgv;
#pragma unroll
  for (int i = 0; i < 32; ++i) {
    float4 a = wa4[i], x = kv4[i];
    K2v += a.x * x.x + a.y * x.y + a.z * x.z + a.w * x.w;
  }
  out[OQG + bn * 128 + h] = Qv;
  out[OKG2 + bn * 128 + h] = K2v;
}

// K6: logits[m] = Qg[bn,:]·Kg2[b,m,:]; softmax over m; *adj -> adj2
__global__ __launch_bounds__(384) void k6_attn(const float* __restrict__ adj, float* out) {
  int bn = blockIdx.x, b = bn / N_, n = bn % N_, tid = threadIdx.x;
  __shared__ float qs[128];
  __shared__ float red1[6], red2[6];
  if (tid < 128) qs[tid] = out[OQG + bn * 128 + tid];
  __syncthreads();
  int m = tid;
  float logit = -3.0e38f;
  if (m < N_) {
    const float4* kr = (const float4*)(out + OKG2 + ((size_t)b * N_ + m) * 128);
    const float4* q4 = (const float4*)qs;
    float a = 0.f;
#pragma unroll
    for (int i = 0; i < 32; ++i) {
      float4 x = kr[i], y = q4[i];
      a += x.x * y.x + x.y * y.y + x.z * y.z + x.w * y.w;
    }
    logit = a;
  }
  float v = logit;
#pragma unroll
  for (int off = 32; off; off >>= 1) v = fmaxf(v, __shfl_xor(v, off));
  int w = tid >> 6, lane = tid & 63;
  if (lane == 0) red1[w] = v;
  __syncthreads();
  float mx = red1[0];
#pragma unroll
  for (int i = 1; i < 6; ++i) mx = fmaxf(mx, red1[i]);
  float ev = (m < N_) ? expf(logit - mx) : 0.f;
  float sv = ev;
#pragma unroll
  for (int off = 32; off; off >>= 1) sv += __shfl_xor(sv, off);
  if (lane == 0) red2[w] = sv;
  __syncthreads();
  float total = 0.f;
#pragma unroll
  for (int i = 0; i < 6; ++i) total += red2[i];
  if (m < N_) out[OADJ2 + (size_t)bn * N_ + m] = (ev / total) * adj[n * N_ + m];
}

// K7: u[bn,t] = sum_m adj2[bn,m] * s[b,m,t]
__global__ __launch_bounds__(320) void k7_u(const float* out, float* __restrict__ ws) {
  int bn = blockIdx.x, b = bn / N_, tid = threadIdx.x;
  __shared__ float arow[N_];
  for (int i = tid; i < N_; i += 320) arow[i] = out[OADJ2 + (size_t)bn * N_ + i];
  __syncthreads();
  if (tid < 288) {
    const float* sb = out + OS + (size_t)b * N_ * 288 + tid;
    float acc = 0.f;
#pragma unroll 8
    for (int m = 0; m < N_; ++m) acc += arow[m] * sb[(size_t)m * 288];
    ws[WU + bn * 288 + tid] = acc;
  }
}

// K8: new_values[bn,t,f] = sum_h gelu(u[bn,t]*gw[h]) * gWout[h,f]
__global__ __launch_bounds__(256) void k8_final(const float* __restrict__ gWout,
                                                const float* __restrict__ ws,
                                                float* __restrict__ out) {
  __shared__ float wo[128 * 64];
  __shared__ float pl[32 * 130];
  __shared__ float gwl[128];
  __shared__ float ul[32];
  int blk = blockIdx.x;
  int bn = blk / 9, t0 = (blk % 9) * 32;
  int tid = threadIdx.x;
  const float4* src = (const float4*)gWout;
  float4* dst = (float4*)wo;
  for (int i = tid; i < 2048; i += 256) dst[i] = src[i];
  if (tid < 128) gwl[tid] = ws[WGW + tid];
  if (tid < 32) ul[tid] = ws[WU + bn * 288 + t0 + tid];
  __syncthreads();
#pragma unroll
  for (int j = 0; j < 16; ++j) {
    int i = tid + j * 256;
    int t = i >> 7, h = i & 127;
    float x = ul[t] * gwl[h];
    pl[t * 130 + h] = 0.5f * x * (1.0f + erff(x * 0.7071067811865475f));
  }
  __syncthreads();
  int tq = tid >> 4, fq = tid & 15;
  float4 acc0 = {0, 0, 0, 0}, acc1 = {0, 0, 0, 0};
#pragma unroll 8
  for (int h = 0; h < 128; ++h) {
    float4 wv = *(const float4*)&wo[h * 64 + fq * 4];
    float p0 = pl[tq * 130 + h];
    float p1 = pl[(tq + 16) * 130 + h];
    acc0.x += p0 * wv.x; acc0.y += p0 * wv.y; acc0.z += p0 * wv.z; acc0.w += p0 * wv.w;
    acc1.x += p1 * wv.x; acc1.y += p1 * wv.y; acc1.z += p1 * wv.z; acc1.w += p1 * wv.w;
  }
  size_t base = ((size_t)bn * 288 + t0) * 64;
  *(float4*)&out[base + (size_t)tq * 64 + fq * 4] = acc0;
  *(float4*)&out[base + (size_t)(tq + 16) * 64 + fq * 4] = acc1;
}

extern "C" void kernel_launch(void* const* d_in, const int* in_sizes, int n_in,
                              void* d_out, int out_size, void* d_ws, size_t ws_size,
                              hipStream_t stream) {
  const float* Qin = (const float*)d_in[0];
  const float* Kin = (const float*)d_in[1];
  const float* Vin = (const float*)d_in[2];
  const float* adj = (const float*)d_in[3];
  const float* Wq  = (const float*)d_in[4];
  const float* Wk  = (const float*)d_in[5];
  const float* Wv  = (const float*)d_in[6];
  const float* Wout_map = (const float*)d_in[7];
  const float* gQ1 = (const float*)d_in[8];
  const float* gQ2 = (const float*)d_in[9];
  const float* gK1 = (const float*)d_in[10];
  const float* gK2 = (const float*)d_in[11];
  const float* gWa = (const float*)d_in[12];
  const float* gWg = (const float*)d_in[13];
  const float* gWout = (const float*)d_in[14];
  float* out = (float*)d_out;
  float* ws = (float*)d_ws;

  k0_prep<<<1, 128, 0, stream>>>(Wout_map, gWg, Wq, Wk, ws, out);
  k1_fused<<<BN_, 256, 0, stream>>>(Qin, Kin, out);
  k2_vs<<<BN_, 256, 0, stream>>>(Vin, Wv, gQ1, gK1, out, ws);
  k5_qkg<<<BN_, 128, 0, stream>>>(gQ2, gK2, gWa, out, ws);
  k6_attn<<<BN_, 384, 0, stream>>>(adj, out);
  k7_u<<<BN_, 320, 0, stream>>>(out, ws);
  k8_final<<<BN_ * 9, 256, 0, stream>>>(gWout, ws, out);
}